// Round 5
// baseline (194.643 us; speedup 1.0000x reference)
//
#include <hip/hip_runtime.h>
#include <float.h>
#include <math.h>

// Problem constants
#define BATCH   8192
#define NCH     45
#define SEQL    21
#define NEXP    22
#define ROWLEN  945          // NCH*SEQL
#define GOFF    7741440      // BATCH*ROWLEN, start of A_flat in d_out
#define K1_BLOCKS 2048       // 4 batches per block, one per wave
#define K3_BLOCKS 4096       // 2 batches per block
#define NSLOT   8            // split-atomic slots for the channel-mean reduce
#define LOG2E   1.4426950408889634f

typedef float vfloat2 __attribute__((ext_vector_type(2)));   // native vec for NT stores

__device__ __forceinline__ float fast_tanh(float v) {
    const float t = __expf(2.f * v);
    return (t - 1.f) / (t + 1.f);
}

__device__ __forceinline__ float fexp2(float v) {
#if defined(__has_builtin)
#if __has_builtin(__builtin_amdgcn_exp2f)
    return __builtin_amdgcn_exp2f(v);     // single v_exp_f32
#else
    return __expf(v * 0.6931471805599453f);
#endif
#else
    return __expf(v * 0.6931471805599453f);
#endif
}

// ---------------- K1: gating (conv -> pools -> 2x MLP -> softmax), barrier-lean ---------
// 4 rows/block, one row per wave. MLP runs in-wave via __shfl (wave-private dataflow):
// only 2 block barriers (stage, final partial). Channel sums go to 8-way split atomics.
__global__ __launch_bounds__(256) void k1_gate(
    const float* __restrict__ x,
    const float* __restrict__ gc_w, const float* __restrict__ gc_b,
    const float* __restrict__ w1,   const float* __restrict__ b1,
    const float* __restrict__ w2,   const float* __restrict__ b2,
    float* __restrict__ gate_out,   float* __restrict__ mg8)
{
    __shared__ float xsh[4 * ROWLEN];       // 15120 B: 4 batch rows
    __shared__ float part[4][NCH];

    const int tid  = threadIdx.x;
    const int w    = tid >> 6;              // wave = local batch row
    const int lane = tid & 63;
    const int b_base = blockIdx.x * 4;

    // stage 4 consecutive batch rows: 945 float4, coalesced (base 15120B-aligned)
    {
        const float4* x4 = (const float4*)(x + (size_t)b_base * ROWLEN);
        float4* xsh4 = (float4*)xsh;
        for (int q = tid; q < 945; q += 256) xsh4[q] = x4[q];
    }
    __syncthreads();

    // ---- conv + pools (all 64 lanes run; lanes>=45 clamped, results unused) ----
    const int ch = (lane < NCH) ? lane : (NCH - 1);
    float xr[SEQL];
    {
        const float* xp = &xsh[w * ROWLEN + ch * SEQL];
        #pragma unroll
        for (int l = 0; l < SEQL; ++l) xr[l] = xp[l];
    }
    float mx = -FLT_MAX, av = 0.f;
    for (int o = 0; o < SEQL; ++o) {
        float t = gc_b[o];
        #pragma unroll
        for (int l = 0; l < SEQL; ++l) t = fmaf(gc_w[o * SEQL + l], xr[l], t);
        mx = fmaxf(mx, t);
        av += t;
    }
    av *= (1.f / 21.f);

    // ---- MLP layer 1 (25 outputs; lane j computes h_j), wave-internal shuffles ----
    const int jj = (lane < 25) ? lane : 24;
    float tm = b1[jj], ta = b1[jj];
    for (int i = 0; i < NCH; ++i) {
        const float wv_ = w1[jj * NCH + i];
        tm = fmaf(wv_, __shfl(mx, i, 64), tm);
        ta = fmaf(wv_, __shfl(av, i, 64), ta);
    }
    const float hm = fast_tanh(tm);
    const float ha = fast_tanh(ta);

    // ---- MLP layer 2 (45 outputs; lane c computes o_c) ----
    float tm2 = b2[ch], ta2 = b2[ch];
    for (int j = 0; j < 25; ++j) {
        const float wv_ = w2[ch * 25 + j];
        tm2 = fmaf(wv_, __shfl(hm, j, 64), tm2);
        ta2 = fmaf(wv_, __shfl(ha, j, 64), ta2);
    }
    // combine + softmax over channels; exp arg in [-2,2], no max-sub needed
    float g = (lane < NCH) ? __expf(fast_tanh(tm2) + fast_tanh(ta2)) : 0.f;
    float s = g;
    #pragma unroll
    for (int off = 32; off > 0; off >>= 1) s += __shfl_xor(s, off, 64);
    const float gt = g / s;

    if (lane < NCH) {
        gate_out[(size_t)(b_base + w) * NCH + lane] = gt;
        part[w][lane] = gt;
    }
    __syncthreads();
    if (tid < NCH) {
        // 8-way split atomic: chain length 2048/8 = 256 per address
        atomicAdd(&mg8[tid * NSLOT + (blockIdx.x & (NSLOT - 1))],
                  part[0][tid] + part[1][tid] + part[2][tid] + part[3][tid]);
    }
}

// ---------------- K3: top-k + expert scalars (redundant per block) + attention -----------
// 2 rows/block; 15.5 KB LDS -> 8 blocks/CU. Nontemporal output stores.
__global__ __launch_bounds__(256) void k3_attn(
    const float* __restrict__ x, const float* __restrict__ gate,
    const float* __restrict__ mg8,
    const float* __restrict__ wq, const float* __restrict__ bq,
    const float* __restrict__ wk, const float* __restrict__ bk,
    const float* __restrict__ wv, const float* __restrict__ bv,
    const float* __restrict__ wo, const float* __restrict__ bo,
    float* __restrict__ out)
{
    __shared__ float xsh[2 * ROWLEN];   // 7560 B: 2 batch rows of x
    __shared__ float ash[2 * ROWLEN];   // 7560 B: full A image incl. zeros
    __shared__ float smg[64];
    __shared__ float gat[2][NEXP];
    __shared__ float sA[NEXP], sC[NEXP], sP[NEXP], sQ[NEXP];
    __shared__ int   ssel[NEXP];

    const int tid = threadIdx.x;
    const int b0  = blockIdx.x * 2;

    // stage 2 rows of x (945 float2) + zero the A image — issue memory first
    {
        const float2* x2 = (const float2*)(x + (size_t)b0 * ROWLEN);
        float2* xsh2 = (float2*)xsh;
        float2* ash2 = (float2*)ash;
        const float2 z = make_float2(0.f, 0.f);
        for (int q = tid; q < 945; q += 256) {
            xsh2[q] = x2[q];
            ash2[q] = z;
        }
    }

    // wave 0: channel means from the 8 split slots
    if (tid < 64) {
        float s = -FLT_MAX;
        if (tid < NCH) {
            const float4* p = (const float4*)(mg8 + tid * NSLOT);
            const float4 a = p[0], b = p[1];
            s = ((a.x + a.y) + (a.z + a.w)) + ((b.x + b.y) + (b.z + b.w));
        }
        smg[tid] = s;
    }
    // wave 1: per-expert scalars (selection-independent, tiny, L2-hot weights)
    if (tid >= 64 && tid < 64 + NEXP) {
        const int e = tid - 64;
        float A = 0.f, Cc = 0.f, P = 0.f, Q = 0.f;
        for (int i = 0; i < SEQL; ++i) {
            A  = fmaf(wq[e * SEQL + i], wk[e * SEQL + i], A);
            Cc = fmaf(bq[e * SEQL + i], wk[e * SEQL + i], Cc);
            P  = fmaf(wo[e * SEQL + i], wv[e * SEQL + i], P);
            Q  = fmaf(wo[e * SEQL + i], bv[e * SEQL + i], Q);
        }
        sA[e] = A * LOG2E;          // fold log2(e): K3 uses bare v_exp_f32
        sC[e] = Cc * LOG2E;
        sP[e] = P;
        sQ[e] = Q + bo[e];
    }
    __syncthreads();

    // wave-0 ballot top-22: rank channel t among 45 (ties -> lower index wins)
    if (tid < 64) {
        const float v = smg[tid];
        int rank = 0;
        #pragma unroll
        for (int i = 0; i < NCH; ++i) {
            const float u = smg[i];
            rank += (u > v || (u == v && i < tid)) ? 1 : 0;
        }
        const bool seld = (tid < NCH) && (rank < NEXP);
        const unsigned long long m = __ballot(seld);
        if (seld) {
            const int e = __popcll(m & ((1ull << tid) - 1ull));
            ssel[e] = tid;
        }
    }
    __syncthreads();

    if (tid < 2 * NEXP) {               // gates for 2 batches x 22 selected channels
        const int bi = (tid >= NEXP) ? 1 : 0;
        const int e  = tid - bi * NEXP;
        gat[bi][e] = gate[(size_t)(b0 + bi) * NCH + ssel[e]];
    }
    __syncthreads();

    // Full-packed compute: 924 l-tasks, thread owns a contiguous range (3-4 tasks,
    // spanning at most 2 (b,e) rows). Row cached in registers, m-loop unrolled.
    {
        const int t0 = (tid * 924) >> 8;
        const int t1 = ((tid + 1) * 924) >> 8;
        int cur_be = -1;
        float xr[SEQL];
        float Ae = 0.f, Ce = 0.f, Pe = 0.f, Qe = 0.f, ge = 0.f;
        const float* xp = nullptr;
        float* ap = nullptr;

        for (int tsk = t0; tsk < t1; ++tsk) {
            const int be = (tsk * 3121) >> 16;          // tsk/21, exact for tsk<1848
            if (be != cur_be) {
                cur_be = be;
                const int bi = (be * 2979) >> 16;       // be/22, exact for be<88
                const int e  = be - bi * NEXP;
                xp = &xsh[bi * ROWLEN + ssel[e] * SEQL];
                ap = &ash[bi * ROWLEN + ssel[e] * SEQL];
                #pragma unroll
                for (int m = 0; m < SEQL; ++m) xr[m] = xp[m];
                Ae = sA[e]; Ce = sC[e]; Pe = sP[e]; Qe = sQ[e];
                ge = gat[bi][e];
            }
            const int l = tsk - cur_be * SEQL;
            const float al2 = fmaf(Ae, xp[l], Ce);      // log2-domain alpha
            float den = 0.f, num = 0.f;
            #pragma unroll
            for (int m = 0; m < SEQL; ++m) {
                const float wgt = fexp2(al2 * xr[m]);
                den += wgt;
                num = fmaf(xr[m], wgt, num);
            }
            ap[l] = fmaf(Pe, __fdividef(num, den), Qe) * ge;
        }
    }
    __syncthreads();

    // nontemporal coalesced 8B writes: G = A .* x, then A (output never re-read)
    {
        const float* xs = xsh;
        const float* as = ash;
        vfloat2* g2 = (vfloat2*)out + (size_t)blockIdx.x * 945;
        vfloat2* a2 = (vfloat2*)(out + (size_t)GOFF) + (size_t)blockIdx.x * 945;
        for (int q = tid; q < 945; q += 256) {
            const float a0 = as[2 * q],     a1 = as[2 * q + 1];
            const float x0 = xs[2 * q],     x1 = xs[2 * q + 1];
            vfloat2 gv; gv.x = a0 * x0; gv.y = a1 * x1;
            vfloat2 av_; av_.x = a0;    av_.y = a1;
            __builtin_nontemporal_store(gv, &g2[q]);
            __builtin_nontemporal_store(av_, &a2[q]);
        }
    }
}

extern "C" void kernel_launch(void* const* d_in, const int* in_sizes, int n_in,
                              void* d_out, int out_size, void* d_ws, size_t ws_size,
                              hipStream_t stream)
{
    const float* x    = (const float*)d_in[0];
    const float* gc_w = (const float*)d_in[1];
    const float* gc_b = (const float*)d_in[2];
    const float* w1   = (const float*)d_in[3];
    const float* b1   = (const float*)d_in[4];
    const float* w2   = (const float*)d_in[5];
    const float* b2   = (const float*)d_in[6];
    const float* wq   = (const float*)d_in[7];
    const float* bq   = (const float*)d_in[8];
    const float* wk   = (const float*)d_in[9];
    const float* bk   = (const float*)d_in[10];
    const float* wv   = (const float*)d_in[11];
    const float* bv   = (const float*)d_in[12];
    const float* wo   = (const float*)d_in[13];
    const float* bo   = (const float*)d_in[14];

    float* ws      = (float*)d_ws;
    float* mg8     = ws;                 // 45*8 = 360 floats (pad to 384)
    float* gateBuf = ws + 384;           // BATCH*45 = 368640 floats
    float* outF    = (float*)d_out;

    // zero the split-atomic accumulator (workspace is poisoned each iteration)
    (void)hipMemsetAsync(mg8, 0, NCH * NSLOT * sizeof(float), stream);

    k1_gate<<<dim3(K1_BLOCKS), dim3(256), 0, stream>>>(x, gc_w, gc_b, w1, b1, w2, b2,
                                                       gateBuf, mg8);
    k3_attn<<<dim3(K3_BLOCKS), dim3(256), 0, stream>>>(x, gateBuf, mg8,
                                                       wq, bq, wk, bk, wv, bv, wo, bo,
                                                       outF);
}

// Round 6
// 149.756 us; speedup vs baseline: 1.2997x; 1.2997x over previous
//
#include <hip/hip_runtime.h>
#include <float.h>
#include <math.h>

// Problem constants
#define BATCH   8192
#define NCH     45
#define SEQL    21
#define NEXP    22
#define ROWLEN  945          // NCH*SEQL
#define GOFF    7741440      // BATCH*ROWLEN, start of A_flat in d_out
#define K1_BLOCKS 2048       // 4 batches per block, one per wave
#define K3_BLOCKS 2048       // persistent: 4 batches per block, 2 chunks of 2
#define LOG2E   1.4426950408889634f

__device__ __forceinline__ float fast_tanh(float v) {
    const float t = __expf(2.f * v);
    return (t - 1.f) / (t + 1.f);
}

__device__ __forceinline__ float fexp2(float v) {
#if defined(__has_builtin)
#if __has_builtin(__builtin_amdgcn_exp2f)
    return __builtin_amdgcn_exp2f(v);     // single v_exp_f32
#else
    return __expf(v * 0.6931471805599453f);
#endif
#else
    return __expf(v * 0.6931471805599453f);
#endif
}

// ---------------- K1: gating (conv -> max/avg pool -> 2x MLP -> softmax) ----------------
// 4 rows per block, one row per wave; 15.4 KB LDS -> 8 blocks/CU -> 32 waves/CU.
// (R3-proven version: LDS-buffer MLP, partialsT reduce — no shuffles, no atomics.)
__global__ __launch_bounds__(256) void k1_gate(
    const float* __restrict__ x,
    const float* __restrict__ gc_w, const float* __restrict__ gc_b,
    const float* __restrict__ w1,   const float* __restrict__ b1,
    const float* __restrict__ w2,   const float* __restrict__ b2,
    float* __restrict__ gate_out,   float* __restrict__ partialsT)
{
    __shared__ float xsh[4 * ROWLEN];       // 15120 B: 4 batch rows
    __shared__ float b45a[4][45];
    __shared__ float b45b[4][45];
    __shared__ float b25a[4][25];
    __shared__ float b25b[4][25];

    const int tid  = threadIdx.x;
    const int w    = tid >> 6;              // wave = local batch row
    const int lane = tid & 63;
    const int b_base = blockIdx.x * 4;

    // stage 4 consecutive batch rows: 945 float4, coalesced (base 15120B-aligned)
    {
        const float4* x4 = (const float4*)(x + (size_t)b_base * ROWLEN);
        float4* xsh4 = (float4*)xsh;
        for (int q = tid; q < 945; q += 256) xsh4[q] = x4[q];
    }
    __syncthreads();

    float g = 0.f;
    if (lane < NCH) {
        // conv: temp[o] = gc_b[o] + sum_l gc_w[o,l]*x[b,lane,l]; pool over o
        float xr[SEQL];
        const float* xp = &xsh[w * ROWLEN + lane * SEQL];
        #pragma unroll
        for (int l = 0; l < SEQL; ++l) xr[l] = xp[l];
        float mx = -FLT_MAX, av = 0.f;
        for (int o = 0; o < SEQL; ++o) {
            float t = gc_b[o];
            #pragma unroll
            for (int l = 0; l < SEQL; ++l) t = fmaf(gc_w[o * SEQL + l], xr[l], t);
            mx = fmaxf(mx, t);
            av += t;
        }
        av *= (1.f / 21.f);
        b45a[w][lane] = mx;
        b45b[w][lane] = av;
    }
    __syncthreads();
    if (lane < 25) {   // layer 1 (shared weights, two inputs mx/av)
        float tm = b1[lane], ta = b1[lane];
        for (int i = 0; i < NCH; ++i) {
            const float wv_ = w1[lane * NCH + i];
            tm = fmaf(wv_, b45a[w][i], tm);
            ta = fmaf(wv_, b45b[w][i], ta);
        }
        b25a[w][lane] = fast_tanh(tm);
        b25b[w][lane] = fast_tanh(ta);
    }
    __syncthreads();
    if (lane < NCH) {  // layer 2 + combine; exp without max (arg in [-2,2], safe)
        float tm = b2[lane], ta = b2[lane];
        for (int j = 0; j < 25; ++j) {
            const float wv_ = w2[lane * 25 + j];
            tm = fmaf(wv_, b25a[w][j], tm);
            ta = fmaf(wv_, b25b[w][j], ta);
        }
        g = __expf(fast_tanh(tm) + fast_tanh(ta));
        b45a[w][lane] = g;
    }
    __syncthreads();
    if (lane < NCH) {
        float s = 0.f;
        for (int i = 0; i < NCH; ++i) s += b45a[w][i];
        const float gt = g / s;
        gate_out[(size_t)(b_base + w) * NCH + lane] = gt;
        b45b[w][lane] = gt;                 // reuse buffer for the per-block partial
    }
    __syncthreads();
    if (tid < NCH) {
        // channel-major partials: K2 block c reads a contiguous 8KB row
        partialsT[tid * K1_BLOCKS + blockIdx.x] =
            b45b[0][tid] + b45b[1][tid] + b45b[2][tid] + b45b[3][tid];
    }
}

// ---------------- K2: 46 blocks — per-channel reduce (0..44) + expert scalars (45) -------
__global__ __launch_bounds__(256) void k2_reduce(
    const float* __restrict__ partialsT,
    const float* __restrict__ wq, const float* __restrict__ bq,
    const float* __restrict__ wk, const float* __restrict__ bk,
    const float* __restrict__ wv, const float* __restrict__ bv,
    const float* __restrict__ wo, const float* __restrict__ bo,
    float* __restrict__ mg, float* __restrict__ escal)
{
    const int tid = threadIdx.x;
    const int c   = blockIdx.x;

    if (c < NCH) {
        // 256 threads x two float4 = all 2048 partials of channel c (contiguous)
        __shared__ float wsum[4];
        const float4* p4 = (const float4*)(partialsT + c * K1_BLOCKS);
        const float4 v0 = p4[tid];
        const float4 v1 = p4[tid + 256];
        float s = ((v0.x + v0.y) + (v0.z + v0.w)) + ((v1.x + v1.y) + (v1.z + v1.w));
        #pragma unroll
        for (int off = 32; off > 0; off >>= 1) s += __shfl_xor(s, off, 64);
        if ((tid & 63) == 0) wsum[tid >> 6] = s;
        __syncthreads();
        if (tid == 0) mg[c] = (wsum[0] + wsum[1]) + (wsum[2] + wsum[3]);
    } else {
        if (tid < NEXP) {    // per-expert scalars (independent of selection)
            const int e = tid;
            float A = 0.f, Cc = 0.f, P = 0.f, Q = 0.f;
            for (int i = 0; i < SEQL; ++i) {
                A  = fmaf(wq[e * SEQL + i], wk[e * SEQL + i], A);
                Cc = fmaf(bq[e * SEQL + i], wk[e * SEQL + i], Cc);
                P  = fmaf(wo[e * SEQL + i], wv[e * SEQL + i], P);
                Q  = fmaf(wo[e * SEQL + i], bv[e * SEQL + i], Q);
            }
            Q += bo[e];
            // fold log2(e) into A,C so K3 uses a bare v_exp_f32
            escal[e]      = A  * LOG2E;
            escal[22 + e] = Cc * LOG2E;
            escal[44 + e] = P;
            escal[66 + e] = Q;
        }
    }
}

// ---------------- K3: persistent — setup once, then 2 chunks of 2 rows -------------------
// 15.5 KB LDS -> 8 blocks/CU -> exactly one residency round at grid 2048.
__global__ __launch_bounds__(256) void k3_attn(
    const float* __restrict__ x, const float* __restrict__ gate,
    const float* __restrict__ mg, const float* __restrict__ escal,
    float* __restrict__ out)
{
    __shared__ float xsh[2 * ROWLEN];   // 7560 B: 2 batch rows of x
    __shared__ float ash[2 * ROWLEN];   // 7560 B: full A image incl. zeros
    __shared__ float smg[64];
    __shared__ float gat[2][NEXP];
    __shared__ float sA[NEXP], sC[NEXP], sP[NEXP], sQ[NEXP];
    __shared__ int   ssel[NEXP];

    const int tid = threadIdx.x;

    // ---- one-time setup: channel means, expert scalars, top-k ----
    if (tid < 64) smg[tid] = (tid < NCH) ? mg[tid] : -FLT_MAX;
    if (tid >= 64 && tid < 64 + NEXP) {
        const int e = tid - 64;
        sA[e] = escal[e];       sC[e] = escal[22 + e];   // already log2e-scaled
        sP[e] = escal[44 + e];  sQ[e] = escal[66 + e];
    }
    __syncthreads();

    // wave-0 ballot top-22: rank channel t among 45 (ties -> lower index wins)
    if (tid < 64) {
        const float v = smg[tid];
        int rank = 0;
        #pragma unroll
        for (int i = 0; i < NCH; ++i) {
            const float u = smg[i];
            rank += (u > v || (u == v && i < tid)) ? 1 : 0;
        }
        const bool seld = (tid < NCH) && (rank < NEXP);
        const unsigned long long m = __ballot(seld);
        if (seld) {
            const int e = __popcll(m & ((1ull << tid) - 1ull));
            ssel[e] = tid;
        }
    }
    __syncthreads();

    // ---- 2 chunks x 2 batch rows ----
    for (int ck = 0; ck < 2; ++ck) {
        const int b0 = blockIdx.x * 4 + ck * 2;

        // stage 2 rows of x (945 float2, base 8B-aligned) + zero the A image
        {
            const float2* x2 = (const float2*)(x + (size_t)b0 * ROWLEN);
            float2* xsh2 = (float2*)xsh;
            float2* ash2 = (float2*)ash;
            const float2 z = make_float2(0.f, 0.f);
            for (int q = tid; q < 945; q += 256) {
                xsh2[q] = x2[q];
                ash2[q] = z;
            }
        }
        if (tid < 2 * NEXP) {           // gates for 2 batches x 22 selected channels
            const int bi = (tid >= NEXP) ? 1 : 0;
            const int e  = tid - bi * NEXP;
            gat[bi][e] = gate[(size_t)(b0 + bi) * NCH + ssel[e]];
        }
        __syncthreads();

        // Full-packed compute: 924 l-tasks, thread owns a contiguous range (3-4 tasks,
        // spanning at most 2 (b,e) rows). Row cached in registers, m-loop unrolled.
        {
            const int t0 = (tid * 924) >> 8;
            const int t1 = ((tid + 1) * 924) >> 8;
            int cur_be = -1;
            float xr[SEQL];
            float Ae = 0.f, Ce = 0.f, Pe = 0.f, Qe = 0.f, ge = 0.f;
            const float* xp = nullptr;
            float* ap = nullptr;

            for (int tsk = t0; tsk < t1; ++tsk) {
                const int be = (tsk * 3121) >> 16;          // tsk/21, exact for tsk<1848
                if (be != cur_be) {
                    cur_be = be;
                    const int bi = (be * 2979) >> 16;       // be/22, exact for be<88
                    const int e  = be - bi * NEXP;
                    xp = &xsh[bi * ROWLEN + ssel[e] * SEQL];
                    ap = &ash[bi * ROWLEN + ssel[e] * SEQL];
                    #pragma unroll
                    for (int m = 0; m < SEQL; ++m) xr[m] = xp[m];
                    Ae = sA[e]; Ce = sC[e]; Pe = sP[e]; Qe = sQ[e];
                    ge = gat[bi][e];
                }
                const int l = tsk - cur_be * SEQL;
                const float al2 = fmaf(Ae, xp[l], Ce);      // log2-domain alpha
                float den = 0.f, num = 0.f;
                #pragma unroll
                for (int m = 0; m < SEQL; ++m) {
                    const float wgt = fexp2(al2 * xr[m]);
                    den += wgt;
                    num = fmaf(xr[m], wgt, num);
                }
                ap[l] = fmaf(Pe, __fdividef(num, den), Qe) * ge;
            }
        }
        __syncthreads();

        // coalesced float2 writes: G = A .* x, then A
        {
            const float2* xsh2 = (const float2*)xsh;
            const float2* ash2 = (const float2*)ash;
            float2* g2 = (float2*)out + (size_t)(blockIdx.x * 2 + ck) * 945;
            float2* a2 = (float2*)(out + (size_t)GOFF) + (size_t)(blockIdx.x * 2 + ck) * 945;
            for (int q = tid; q < 945; q += 256) {
                const float2 a = ash2[q];
                const float2 xv = xsh2[q];
                g2[q] = make_float2(a.x * xv.x, a.y * xv.y);
                a2[q] = a;
            }
        }
        if (ck == 0) __syncthreads();   // protect xsh/ash before next chunk's staging
    }
}

extern "C" void kernel_launch(void* const* d_in, const int* in_sizes, int n_in,
                              void* d_out, int out_size, void* d_ws, size_t ws_size,
                              hipStream_t stream)
{
    const float* x    = (const float*)d_in[0];
    const float* gc_w = (const float*)d_in[1];
    const float* gc_b = (const float*)d_in[2];
    const float* w1   = (const float*)d_in[3];
    const float* b1   = (const float*)d_in[4];
    const float* w2   = (const float*)d_in[5];
    const float* b2   = (const float*)d_in[6];
    const float* wq   = (const float*)d_in[7];
    const float* bq   = (const float*)d_in[8];
    const float* wk   = (const float*)d_in[9];
    const float* bk   = (const float*)d_in[10];
    const float* wv   = (const float*)d_in[11];
    const float* bv   = (const float*)d_in[12];
    const float* wo   = (const float*)d_in[13];
    const float* bo   = (const float*)d_in[14];

    float* ws        = (float*)d_ws;
    float* partialsT = ws;                       // 45*2048 = 92160 floats (channel-major)
    float* mg        = ws + 92160;               // 45 floats (pad to 64)
    float* escal     = ws + 92224;               // 88 floats (A,C,P,Q per expert), pad 128
    float* gateBuf   = ws + 92352;               // BATCH*45 = 368640 floats
    float* outF      = (float*)d_out;

    k1_gate<<<dim3(K1_BLOCKS), dim3(256), 0, stream>>>(x, gc_w, gc_b, w1, b1, w2, b2,
                                                       gateBuf, partialsT);
    k2_reduce<<<dim3(46), dim3(256), 0, stream>>>(partialsT, wq, bq, wk, bk, wv, bv,
                                                  wo, bo, mg, escal);
    k3_attn<<<dim3(K3_BLOCKS), dim3(256), 0, stream>>>(x, gateBuf, mg, escal, outF);
}